// Round 3
// baseline (909.204 us; speedup 1.0000x reference)
//
#include <hip/hip_runtime.h>
#include <math.h>

#define N_NODES 50000
#define N_EDGES 800000
#define CLAMP_V 5.0f
#define EPS_V   1e-8f

// ============================================================================
// K1: QKV projection.  x(50000,64) @ [Wq|Wk|Wv](64,192) + bias -> qkv(50000,192)
// qkv row layout: [Q(64) | K(64) | V(64)], col = h*8+d (matches reshape(n,8,8)).
// ============================================================================
__global__ __launch_bounds__(192) void qkv_kernel(
    const float* __restrict__ x,
    const float* __restrict__ Wq, const float* __restrict__ bq,
    const float* __restrict__ Wk, const float* __restrict__ bk,
    const float* __restrict__ Wv, const float* __restrict__ bv,
    float* __restrict__ qkv)
{
  __shared__ float sW[64][192];
  __shared__ float sb[192];
  __shared__ float sa[16][68];
  const int t = threadIdx.x;
  // vectorized weight staging: 3 x (64x64) floats = 3072 float4, 16 per thread
  for (int i = t; i < 3072; i += 192) {
    const int w = i >> 10;            // 0=q 1=k 2=v
    const int r = (i >> 4) & 63;      // k row
    const int c4 = (i & 15) * 4;      // col quad
    const float* W = (w == 0) ? Wq : (w == 1) ? Wk : Wv;
    *(float4*)&sW[r][w*64 + c4] = *(const float4*)&W[r*64 + c4];
  }
  sb[t] = (t < 64) ? bq[t] : (t < 128) ? bk[t-64] : bv[t-128];
  const int n0 = blockIdx.x * 16;
  for (int idx = t; idx < 256; idx += 192) {
    int node = idx >> 4, kq = idx & 15;
    *(float4*)&sa[node][kq*4] = *(const float4*)&x[(size_t)(n0+node)*64 + kq*4];
  }
  __syncthreads();
  float acc[16];
  #pragma unroll
  for (int j = 0; j < 16; j++) acc[j] = 0.f;
  for (int k4 = 0; k4 < 16; k4++) {
    float wq[4];
    #pragma unroll
    for (int q = 0; q < 4; q++) wq[q] = sW[k4*4+q][t];
    #pragma unroll
    for (int jh = 0; jh < 2; jh++) {
      float4 av[8];
      #pragma unroll
      for (int jj = 0; jj < 8; jj++) av[jj] = *(const float4*)&sa[jh*8+jj][k4*4];
      #pragma unroll
      for (int jj = 0; jj < 8; jj++) {
        acc[jh*8+jj] += av[jj].x*wq[0] + av[jj].y*wq[1] + av[jj].z*wq[2] + av[jj].w*wq[3];
      }
    }
  }
  const float b = sb[t];
  #pragma unroll
  for (int j = 0; j < 16; j++) qkv[(size_t)(n0+j)*192 + t] = acc[j] + b;
}

// ============================================================================
// K2: edge kernel, k-split staging (two 32-k phases, single LDS buffer).
// __launch_bounds__(256,4): VGPR cap 128 -- static need ~114 (64 acc + 32 av
// + 8 w + addr). R2's VGPR=84 forced LDS-operand rematerialization (VALUBusy
// 61% vs 28% expected; duration insensitive to occupancy = per-CU LDS/VALU
// issue saturated). LDS 34.8KB -> 4 blocks/CU, matching 4 waves/EU.
// fp32 on purpose: signed-sqrt derivative ~1/(2*sqrt(eps)) near 0 amplifies
// any GEMM error; bf16 would fail tolerance.
// ============================================================================
__global__ __launch_bounds__(256, 4) void edge_kernel(
    const float* __restrict__ edge_attr,
    const int*   __restrict__ eidx,
    const float* __restrict__ We, const float* __restrict__ be,
    const float* __restrict__ Aw,
    const float* __restrict__ qkv,
    float* __restrict__ wE, float* __restrict__ sExp)
{
  __shared__ float sW[32][136];   // col c at c + 8*(c>>6)
  __shared__ float sA[128][32];   // k-quad XOR-swizzled by (row>>3)&3
  __shared__ float sbe[128];
  __shared__ float sAw[64];
  const int t = threadIdx.x;
  const int e0 = blockIdx.x * 128;
  const int te = t >> 4;
  const int g = t & 15, h = g >> 1, dq = g & 1;
  const int cw = h*16 + dq*4, cb = cw + 8;
  const int cwp = cw + 8*(h>>2), cbp = cb + 8*(h>>2);
  const int swa = te & 3;
  float4 accw[8], accb[8];
  #pragma unroll
  for (int j = 0; j < 8; j++) { accw[j] = make_float4(0,0,0,0); accb[j] = make_float4(0,0,0,0); }
  if (t < 128)       sbe[t] = be[t];
  else if (t < 192)  sAw[t-128] = Aw[t-128];

  for (int ph = 0; ph < 2; ph++) {
    if (ph) __syncthreads();
    for (int i = t; i < 1024; i += 256) {
      int k = i >> 5, c = (i & 31) * 4;
      *(float4*)&sW[k][c + 8*(c>>6)] = *(const float4*)&We[(size_t)(ph*32+k)*128 + c];
    }
    for (int i = t; i < 1024; i += 256) {
      int e = i >> 3, kq = i & 7;
      *(float4*)&sA[e][(kq ^ ((e>>3)&3)) * 4] =
          *(const float4*)&edge_attr[(size_t)(e0+e)*64 + ph*32 + kq*4];
    }
    __syncthreads();
    for (int kq = 0; kq < 8; kq++) {
      float4 av[8];
      const int kcol = (kq ^ swa) * 4;
      #pragma unroll
      for (int j = 0; j < 8; j++) av[j] = *(const float4*)&sA[te*8+j][kcol];
      #pragma unroll
      for (int q = 0; q < 4; q++) {
        const int k = kq*4 + q;
        const float4 ww = *(const float4*)&sW[k][cwp];
        const float4 wb = *(const float4*)&sW[k][cbp];
        #pragma unroll
        for (int j = 0; j < 8; j++) {
          const float a = (q==0) ? av[j].x : (q==1) ? av[j].y : (q==2) ? av[j].z : av[j].w;
          accw[j].x += a*ww.x; accw[j].y += a*ww.y; accw[j].z += a*ww.z; accw[j].w += a*ww.w;
          accb[j].x += a*wb.x; accb[j].y += a*wb.y; accb[j].z += a*wb.z; accb[j].w += a*wb.w;
        }
      }
    }
  }

  const float4 bw = *(const float4*)&sbe[cw];
  const float4 bb = *(const float4*)&sbe[cb];
  const int d0 = dq * 4;
  const float awc0 = sAw[(d0+0)*8+h], awc1 = sAw[(d0+1)*8+h];
  const float awc2 = sAw[(d0+2)*8+h], awc3 = sAw[(d0+3)*8+h];
  #pragma unroll
  for (int j = 0; j < 8; j++) {
    const int e   = e0 + te*8 + j;
    const int src = eidx[e];
    const int dst = eidx[N_EDGES + e];
    const float4 kv = *(const float4*)&qkv[(size_t)src*192 + 64 + h*8 + d0];
    const float4 qv = *(const float4*)&qkv[(size_t)dst*192 +      h*8 + d0];
    const float s0 = (kv.x+qv.x)*(accw[j].x+bw.x);
    const float s1 = (kv.y+qv.y)*(accw[j].y+bw.y);
    const float s2 = (kv.z+qv.z)*(accw[j].z+bw.z);
    const float s3 = (kv.w+qv.w)*(accw[j].w+bw.w);
    const float r0 = sqrtf(fmaxf(s0,0.f)+EPS_V) - sqrtf(fmaxf(-s0,0.f)+EPS_V) + (accb[j].x+bb.x);
    const float r1 = sqrtf(fmaxf(s1,0.f)+EPS_V) - sqrtf(fmaxf(-s1,0.f)+EPS_V) + (accb[j].y+bb.y);
    const float r2 = sqrtf(fmaxf(s2,0.f)+EPS_V) - sqrtf(fmaxf(-s2,0.f)+EPS_V) + (accb[j].z+bb.z);
    const float r3 = sqrtf(fmaxf(s3,0.f)+EPS_V) - sqrtf(fmaxf(-s3,0.f)+EPS_V) + (accb[j].w+bb.w);
    *(float4*)&wE[(size_t)e*64 + h*8 + d0] = make_float4(r0,r1,r2,r3);
    float ps = r0*awc0 + r1*awc1 + r2*awc2 + r3*awc3;
    ps += __shfl_xor(ps, 1, 64);
    if (dq == 0) {
      const float sc = fminf(fmaxf(ps, -CLAMP_V), CLAMP_V);
      // segment-max subtraction dropped: s in [-5,5] -> exp safe; denominator
      // perturbation vs reference is ~2e-12 relative.
      sExp[(size_t)e*8 + h] = expf(sc);
    }
  }
}

// ============================================================================
// K3: CSR-by-dst build.
// ============================================================================
__global__ __launch_bounds__(256) void count_kernel(const int* __restrict__ eidx,
                                                    int* __restrict__ deg)
{
  const int e = blockIdx.x*256 + threadIdx.x;
  if (e < N_EDGES) atomicAdd(&deg[eidx[N_EDGES + e]], 1);
}

__global__ __launch_bounds__(1024) void scan_kernel(const int* __restrict__ deg,
                                                    int* __restrict__ row_start,
                                                    int* __restrict__ cursor)
{
  __shared__ int buf[1024];
  const int t = threadIdx.x;
  const int beg = t * 49;
  const int end = (beg + 49 < N_NODES) ? beg + 49 : N_NODES;
  int sum = 0;
  for (int i = beg; i < end; i++) sum += deg[i];
  buf[t] = sum;
  __syncthreads();
  for (int off = 1; off < 1024; off <<= 1) {
    const int v = (t >= off) ? buf[t-off] : 0;
    __syncthreads();
    buf[t] += v;
    __syncthreads();
  }
  int run = (t == 0) ? 0 : buf[t-1];
  for (int i = beg; i < end; i++) {
    const int d = deg[i];
    row_start[i] = run; cursor[i] = run; run += d;
  }
  if (t == 1023) row_start[N_NODES] = buf[1023];
}

__global__ __launch_bounds__(256) void scatter_kernel(const int* __restrict__ eidx,
                                                      int* __restrict__ cursor,
                                                      int* __restrict__ edge_ord,
                                                      int* __restrict__ src_perm)
{
  const int e = blockIdx.x*256 + threadIdx.x;
  if (e < N_EDGES) {
    const int pos = atomicAdd(&cursor[eidx[N_EDGES + e]], 1);
    edge_ord[pos] = e;
    src_perm[pos] = eidx[e];
  }
}

// ============================================================================
// K4: node aggregation. TWO waves per node (parity-strided halves, LDS
// combine) -- halves the per-wave serial chain, doubles load-level
// parallelism per node. Single pass: attn=e/D factors out,
// wV = (sum e*V + (sum e*e_t)@VeRow) / (D+1e-16).
// wE/sExp are use-once streams -> nontemporal.
// ============================================================================
__global__ __launch_bounds__(256) void node_kernel(
    const int*   __restrict__ row_start,
    const int*   __restrict__ edge_ord,
    const int*   __restrict__ src_perm,
    const float* __restrict__ sExp,
    const float* __restrict__ qkv,
    const float* __restrict__ wE,
    const float* __restrict__ VeRow,
    float* __restrict__ wV)
{
  __shared__ float sVe[512];                      // VeRow flat [d][h][c]
  __shared__ float red[2][64][3];                 // parity-1 partials
  const int t = threadIdx.x;
  for (int i = t; i < 512; i += 256) sVe[i] = VeRow[i];
  const int lane = t & 63;
  const int w    = t >> 6;                        // 0..3
  const int nl   = w >> 1;                        // node slot in block
  const int par  = w & 1;                         // which half of the row
  const int node = blockIdx.x*2 + nl;             // 25000*2 == 50000
  const int h = lane >> 3;
  const int rs = row_start[node], re = row_start[node+1];
  float accU = 0.f, accR = 0.f, accD = 0.f;
  int j = rs + par;
  for (; j + 6 < re; j += 8) {                    // 4 slots per wave, stride 2
    const int e0 = edge_ord[j],   e1 = edge_ord[j+2];
    const int e2 = edge_ord[j+4], e3 = edge_ord[j+6];
    const int s0 = src_perm[j],   s1 = src_perm[j+2];
    const int s2 = src_perm[j+4], s3 = src_perm[j+6];
    const float w0 = __builtin_nontemporal_load(&sExp[(size_t)e0*8 + h]);
    const float w1 = __builtin_nontemporal_load(&sExp[(size_t)e1*8 + h]);
    const float w2 = __builtin_nontemporal_load(&sExp[(size_t)e2*8 + h]);
    const float w3 = __builtin_nontemporal_load(&sExp[(size_t)e3*8 + h]);
    const float t0 = __builtin_nontemporal_load(&wE[(size_t)e0*64 + lane]);
    const float t1 = __builtin_nontemporal_load(&wE[(size_t)e1*64 + lane]);
    const float t2 = __builtin_nontemporal_load(&wE[(size_t)e2*64 + lane]);
    const float t3 = __builtin_nontemporal_load(&wE[(size_t)e3*64 + lane]);
    const float v0 = qkv[(size_t)s0*192 + 128 + lane];
    const float v1 = qkv[(size_t)s1*192 + 128 + lane];
    const float v2 = qkv[(size_t)s2*192 + 128 + lane];
    const float v3 = qkv[(size_t)s3*192 + 128 + lane];
    accD += (w0 + w1) + (w2 + w3);
    accU += w0*v0; accU += w1*v1; accU += w2*v2; accU += w3*v3;
    accR += w0*t0; accR += w1*t1; accR += w2*t2; accR += w3*t3;
  }
  for (; j < re; j += 2) {
    const int eid = edge_ord[j];
    const int src = src_perm[j];
    const float ww = __builtin_nontemporal_load(&sExp[(size_t)eid*8 + h]);
    accD += ww;
    accU += ww * qkv[(size_t)src*192 + 128 + lane];
    accR += ww * __builtin_nontemporal_load(&wE[(size_t)eid*64 + lane]);
  }
  if (par == 1) {
    red[nl][lane][0] = accU; red[nl][lane][1] = accR; red[nl][lane][2] = accD;
  }
  __syncthreads();
  if (par == 0) {
    accU += red[nl][lane][0];
    accR += red[nl][lane][1];
    accD += red[nl][lane][2];
    float val = accU;
    #pragma unroll
    for (int dd = 0; dd < 8; dd++) {
      const float rv = __shfl(accR, h*8 + dd, 64);
      val += rv * sVe[dd*64 + lane];
    }
    wV[(size_t)node*64 + lane] = val * (1.0f / (accD + 1e-16f));
  }
}

// ============================================================================
// Workspace layout (bytes, needs ~71.0 MB):
//   qkv      @ 0           : 38,400,000
//   sExp     @ 38,400,000  : 25,600,000
//   deg      @ 64,000,000  :    200,000
//   row_start@ 64,200,000  :    200,004
//   cursor   @ 64,400,208  :    200,000
//   edge_ord @ 64,600,208  :  3,200,000
//   src_perm @ 67,800,208  :  3,200,000
// d_out: wV (50000*64) then wE (800000*64), fp32.
// ============================================================================
extern "C" void kernel_launch(void* const* d_in, const int* in_sizes, int n_in,
                              void* d_out, int out_size, void* d_ws, size_t ws_size,
                              hipStream_t stream)
{
  const float* x         = (const float*)d_in[0];
  const float* edge_attr = (const float*)d_in[1];
  const int*   eidx      = (const int*)  d_in[2];
  const float* Wq        = (const float*)d_in[3];
  const float* bq        = (const float*)d_in[4];
  const float* Wk        = (const float*)d_in[5];
  const float* bk        = (const float*)d_in[6];
  const float* We        = (const float*)d_in[7];
  const float* be        = (const float*)d_in[8];
  const float* Wv        = (const float*)d_in[9];
  const float* bv        = (const float*)d_in[10];
  const float* Aw        = (const float*)d_in[11];
  const float* VeRow     = (const float*)d_in[12];

  float* out = (float*)d_out;
  float* wV  = out;
  float* wE  = out + (size_t)N_NODES * 64;

  char* ws = (char*)d_ws;
  float* qkv      = (float*)(ws);
  float* sExp     = (float*)(ws + 38400000);
  int*   deg      = (int*)  (ws + 64000000);
  int*   row_start= (int*)  (ws + 64200000);
  int*   cursor   = (int*)  (ws + 64400208);
  int*   edge_ord = (int*)  (ws + 64600208);
  int*   src_perm = (int*)  (ws + 67800208);

  hipMemsetAsync(deg, 0, N_NODES * sizeof(int), stream);
  qkv_kernel    <<<3125,  192, 0, stream>>>(x, Wq, bq, Wk, bk, Wv, bv, qkv);
  edge_kernel   <<<6250,  256, 0, stream>>>(edge_attr, eidx, We, be, Aw, qkv, wE, sExp);
  count_kernel  <<<3125,  256, 0, stream>>>(eidx, deg);
  scan_kernel   <<<1,    1024, 0, stream>>>(deg, row_start, cursor);
  scatter_kernel<<<3125,  256, 0, stream>>>(eidx, cursor, edge_ord, src_perm);
  node_kernel   <<<25000, 256, 0, stream>>>(row_start, edge_ord, src_perm, sExp, qkv, wE, VeRow, wV);
}